// Round 5
// baseline (459.947 us; speedup 1.0000x reference)
//
#include <hip/hip_runtime.h>
#include <hip/hip_fp16.h>

typedef _Float16 half2_t __attribute__((ext_vector_type(2)));
typedef _Float16 half4_t __attribute__((ext_vector_type(4)));
typedef _Float16 half8_t __attribute__((ext_vector_type(8)));
typedef float   float4_t __attribute__((ext_vector_type(4)));

static __device__ __forceinline__ half2_t cvt_pk(float a, float b) {
    return __builtin_bit_cast(half2_t, __builtin_amdgcn_cvt_pkrtz(a, b));
}
static __device__ __forceinline__ half4_t cvt_pk4(float a, float b, float c, float d) {
    half2_t lo = cvt_pk(a, b), hi = cvt_pk(c, d);
    half4_t r;
    r[0] = lo[0]; r[1] = lo[1]; r[2] = hi[0]; r[3] = hi[1];
    return r;
}

namespace {
constexpr int kB      = 16;    // batch
constexpr int kL      = 4096;  // Lq == Lk
constexpr int kD      = 64;    // head dim
constexpr int kQTile  = 128;   // 4 waves x 32 q-rows (qt=2 amortizes kf/vf LDS reads)
constexpr int kBK     = 64;    // keys per iteration
constexpr int kStride = 72;    // padded LDS row stride (halves)
constexpr size_t kOS  = (size_t)kB * kL * kD;   // floats per partial-O
constexpr size_t kRS  = (size_t)kB * kL;        // rows (for m/l arrays)
// ws layout (floats): O[2][kOS] | m[2][kRS] | l[2][kRS]
constexpr size_t kWsFloats = 2 * kOS + 4 * kRS;
}

// Flash attention fwd v5 = R4 (register prefetch, 4 waves x 32 q-rows) +
// key-dim SPLIT-K (2 splits of 2048 keys): grid 512 -> 1024 blocks = 4
// blocks/CU, doubling co-resident independent blocks so one block's barrier/
// softmax chain overlaps another's MFMA — per-wave inner loop identical to R4
// (R3 showed shrinking per-wave work to raise occupancy backfires).
// Partials (unnormalized O, m, l) -> d_ws; combine kernel merges via LSE.
template <int SPLITS>
__global__ __launch_bounds__(256, 4)
void fa_fwd(const float* __restrict__ Q, const float* __restrict__ K,
            const float* __restrict__ V, const float* __restrict__ scale_ptr,
            float* __restrict__ Out, float* __restrict__ ws)
{
    __shared__ __align__(16) _Float16 Ksh[kBK * kStride];   // Ksh[key][d]
    __shared__ __align__(16) _Float16 Vsh[kD * kStride];    // Vsh[d][key] (transposed)

    const int tid  = threadIdx.x;
    const int wave = tid >> 6;
    const int lane = tid & 63;
    const int c    = lane & 15;   // intra-16 index (q-col in S^T, d-col in O)
    const int qd   = lane >> 4;   // quad 0..3

    const int b   = blockIdx.y;
    const int z   = blockIdx.z;
    const int q0  = blockIdx.x * kQTile + wave * 32;
    const int ks0 = z * (kL / SPLITS);
    const int ks1 = ks0 + kL / SPLITS;

    // fold 1/scale and log2(e) into Q so softmax uses raw exp2
    const float qscale = 1.4426950408889634f / scale_ptr[0];

    const float* Qb = Q + (size_t)b * kL * kD;
    const float* Kb = K + (size_t)b * kL * kD;
    const float* Vb = V + (size_t)b * kL * kD;

    // ---- Q fragments (B-operand of 16x16x32: n=lane&15=qrow, k=8*quad+j=d) ----
    half8_t qfrag[2][2];
#pragma unroll
    for (int qt = 0; qt < 2; ++qt) {
        const float* qrow = Qb + (size_t)(q0 + qt * 16 + c) * kD;
#pragma unroll
        for (int dk = 0; dk < 2; ++dk) {
            const float* p = qrow + dk * 32 + qd * 8;
            half8_t h;
#pragma unroll
            for (int j = 0; j < 8; ++j) h[j] = (_Float16)(p[j] * qscale);
            qfrag[qt][dk] = h;
        }
    }

    float4_t O[2][4];
#pragma unroll
    for (int qt = 0; qt < 2; ++qt)
#pragma unroll
        for (int dt = 0; dt < 4; ++dt) O[qt][dt] = (float4_t)0.0f;

    float m_run[2] = {-__builtin_inff(), -__builtin_inff()};
    float lpart[2] = {0.0f, 0.0f};

    // ---- prefetch first tile into registers ----
    float4 pk[4], pv[4];
#pragma unroll
    for (int i = 0; i < 4; ++i) {
        const int tk = tid + 256 * i;
        pk[i] = *(const float4*)(Kb + (size_t)(ks0 + (tk >> 4)) * kD + (tk & 15) * 4);
        pv[i] = *(const float4*)(Vb + (size_t)(ks0 + (tk & 63)) * kD + (tk >> 6) * 4);
    }

    for (int kb = ks0; kb < ks1; kb += kBK) {
        __syncthreads();  // previous tile's readers done; also drains prefetch vmcnt

        // ---- commit prefetched tile to LDS (fp32 -> fp16) ----
#pragma unroll
        for (int i = 0; i < 4; ++i) {
            const int tk = tid + 256 * i;
            *(half4_t*)(&Ksh[(tk >> 4) * kStride + (tk & 15) * 4]) =
                cvt_pk4(pk[i].x, pk[i].y, pk[i].z, pk[i].w);
        }
#pragma unroll
        for (int i = 0; i < 4; ++i) {
            const int tk  = tid + 256 * i;
            const int row = tk & 63;
            const int c4  = tk >> 6;
            Vsh[(c4 * 4 + 0) * kStride + row] = (_Float16)pv[i].x;
            Vsh[(c4 * 4 + 1) * kStride + row] = (_Float16)pv[i].y;
            Vsh[(c4 * 4 + 2) * kStride + row] = (_Float16)pv[i].z;
            Vsh[(c4 * 4 + 3) * kStride + row] = (_Float16)pv[i].w;
        }
        __syncthreads();

        // ---- prefetch NEXT tile (clamped re-read of first tile on last iter) ----
        {
            const int nb = (kb + kBK < ks1) ? kb + kBK : ks0;
            const float* Kn = Kb + (size_t)nb * kD;
            const float* Vn = Vb + (size_t)nb * kD;
#pragma unroll
            for (int i = 0; i < 4; ++i) {
                const int tk = tid + 256 * i;
                pk[i] = *(const float4*)(Kn + (size_t)(tk >> 4) * kD + (tk & 15) * 4);
                pv[i] = *(const float4*)(Vn + (size_t)(tk & 63) * kD + (tk >> 6) * 4);
            }
        }

        // ---- K fragments (A-operand: m=lane&15=key, k=8*quad+j=d) ----
        half8_t kf[4][2];
#pragma unroll
        for (int kt = 0; kt < 4; ++kt)
#pragma unroll
            for (int dk = 0; dk < 2; ++dk)
                kf[kt][dk] = *(const half8_t*)(&Ksh[(kt * 16 + c) * kStride + dk * 32 + qd * 8]);

        // ---- S^T = K * Q^T  (C-init = -32: free shift, fp16 overflow margin) ----
        float4_t S[4][2];
#pragma unroll
        for (int kt = 0; kt < 4; ++kt)
#pragma unroll
            for (int qt = 0; qt < 2; ++qt) {
                float4_t acc = {-32.0f, -32.0f, -32.0f, -32.0f};
                acc = __builtin_amdgcn_mfma_f32_16x16x32_f16(kf[kt][0], qfrag[qt][0], acc, 0, 0, 0);
                acc = __builtin_amdgcn_mfma_f32_16x16x32_f16(kf[kt][1], qfrag[qt][1], acc, 0, 0, 0);
                S[kt][qt] = acc;
            }

        // ---- online softmax per q-tile (S^T layout: lane column = q-row = c) ----
        half4_t pf[4][2];
#pragma unroll
        for (int qt = 0; qt < 2; ++qt) {
            float tm = S[0][qt][0];
#pragma unroll
            for (int kt = 0; kt < 4; ++kt)
#pragma unroll
                for (int r = 0; r < 4; ++r) tm = fmaxf(tm, S[kt][qt][r]);
            tm = fmaxf(tm, __shfl_xor(tm, 16));
            tm = fmaxf(tm, __shfl_xor(tm, 32));

            const bool newmax = tm > m_run[qt];
            const float mn = newmax ? tm : m_run[qt];
            if (__ballot(newmax)) {  // wave-uniform: skip rescale when no row max moved
                const float alpha = __builtin_amdgcn_exp2f(m_run[qt] - mn);  // 1st iter: 0
                m_run[qt] = mn;
                lpart[qt] *= alpha;
#pragma unroll
                for (int r = 0; r < 4; ++r) {
                    const float a = __shfl(alpha, qd * 4 + r);
#pragma unroll
                    for (int dt = 0; dt < 4; ++dt) O[qt][dt][r] *= a;
                }
            }

            // P = exp2(S - m), per-lane partial l, pack to fp16 A-fragments
#pragma unroll
            for (int kt = 0; kt < 4; ++kt) {
                const float p0 = __builtin_amdgcn_exp2f(S[kt][qt][0] - mn);
                const float p1 = __builtin_amdgcn_exp2f(S[kt][qt][1] - mn);
                const float p2 = __builtin_amdgcn_exp2f(S[kt][qt][2] - mn);
                const float p3 = __builtin_amdgcn_exp2f(S[kt][qt][3] - mn);
                lpart[qt] += (p0 + p1) + (p2 + p3);
                pf[kt][qt] = cvt_pk4(p0, p1, p2, p3);
            }
        }

        // ---- O += P * V  (vf shared across both q-tiles) ----
#pragma unroll
        for (int kt = 0; kt < 4; ++kt)
#pragma unroll
            for (int dt = 0; dt < 4; ++dt) {
                const half4_t vf = *(const half4_t*)(&Vsh[(dt * 16 + c) * kStride + kt * 16 + qd * 4]);
#pragma unroll
                for (int qt = 0; qt < 2; ++qt)
                    O[qt][dt] = __builtin_amdgcn_mfma_f32_16x16x16f16(pf[kt][qt], vf, O[qt][dt], 0, 0, 0);
            }
    }

    // ---- final l reduction (deferred from the loop) ----
#pragma unroll
    for (int qt = 0; qt < 2; ++qt) {
        lpart[qt] += __shfl_xor(lpart[qt], 16);
        lpart[qt] += __shfl_xor(lpart[qt], 32);
    }

    // ---- epilogue ----
#pragma unroll
    for (int qt = 0; qt < 2; ++qt) {
        if (SPLITS == 1) {
#pragma unroll
            for (int r = 0; r < 4; ++r) {
                const float lr  = __shfl(lpart[qt], qd * 4 + r);
                const float inv = 1.0f / lr;
                const int qrow  = q0 + qt * 16 + qd * 4 + r;
                float* op = Out + ((size_t)b * kL + qrow) * kD;
#pragma unroll
                for (int dt = 0; dt < 4; ++dt)
                    op[dt * 16 + c] = O[qt][dt][r] * inv;
            }
        } else {
            // unnormalized partial O + per-row m,l -> workspace
            float* Ow = ws + (size_t)z * kOS;
#pragma unroll
            for (int r = 0; r < 4; ++r) {
                const int qrow = q0 + qt * 16 + qd * 4 + r;
                float* op = Ow + ((size_t)b * kL + qrow) * kD;
#pragma unroll
                for (int dt = 0; dt < 4; ++dt)
                    op[dt * 16 + c] = O[qt][dt][r];
            }
            if (qd == 0) {  // lanes 0..15 hold row (q0+qt*16+c) stats
                const size_t row = (size_t)b * kL + q0 + qt * 16 + c;
                ws[2 * kOS + (size_t)z * kRS + row]           = m_run[qt];
                ws[2 * kOS + 2 * kRS + (size_t)z * kRS + row] = lpart[qt];
            }
        }
    }
}

// merge the 2 key-splits: O = (O0*w0 + O1*w1) / (l0*w0 + l1*w1), wi=exp2(mi-M)
__global__ __launch_bounds__(256)
void fa_combine(const float* __restrict__ ws, float* __restrict__ Out)
{
    const size_t j   = (size_t)blockIdx.x * 256 + threadIdx.x;  // float4 index
    const size_t f   = j * 4;
    const size_t row = f >> 6;  // kD = 64

    const float m0 = ws[2 * kOS + row];
    const float m1 = ws[2 * kOS + kRS + row];
    const float l0 = ws[2 * kOS + 2 * kRS + row];
    const float l1 = ws[2 * kOS + 3 * kRS + row];
    const float M  = fmaxf(m0, m1);
    const float w0 = __builtin_amdgcn_exp2f(m0 - M);
    const float w1 = __builtin_amdgcn_exp2f(m1 - M);
    const float inv = 1.0f / (l0 * w0 + l1 * w1);

    const float4 a = *(const float4*)(ws + f);
    const float4 bq = *(const float4*)(ws + kOS + f);
    float4 o;
    o.x = (a.x * w0 + bq.x * w1) * inv;
    o.y = (a.y * w0 + bq.y * w1) * inv;
    o.z = (a.z * w0 + bq.z * w1) * inv;
    o.w = (a.w * w0 + bq.w * w1) * inv;
    *(float4*)(Out + f) = o;
}

extern "C" void kernel_launch(void* const* d_in, const int* in_sizes, int n_in,
                              void* d_out, int out_size, void* d_ws, size_t ws_size,
                              hipStream_t stream) {
    const float* Q = (const float*)d_in[0];
    const float* K = (const float*)d_in[1];
    const float* V = (const float*)d_in[2];
    const float* s = (const float*)d_in[3];
    float* out = (float*)d_out;
    float* ws  = (float*)d_ws;

    if (ws_size >= kWsFloats * sizeof(float)) {
        dim3 grid(kL / kQTile, kB, 2);
        fa_fwd<2><<<grid, dim3(256, 1, 1), 0, stream>>>(Q, K, V, s, out, ws);
        fa_combine<<<dim3((unsigned)(kOS / (256 * 4))), dim3(256, 1, 1), 0, stream>>>(ws, out);
    } else {
        dim3 grid(kL / kQTile, kB, 1);
        fa_fwd<1><<<grid, dim3(256, 1, 1), 0, stream>>>(Q, K, V, s, out, ws);
    }
}